// Round 5
// baseline (3461.173 us; speedup 1.0000x reference)
//
#include <hip/hip_runtime.h>
#include <hip/hip_bf16.h>
#include <cmath>

// EncoderDecoder: S=49,B=64,DENC=512,DD=1800,DE=512,V=10000,T=20
// Round 5: round-4 pipelined MFMA bf16x3 GEMM with the Q split-K coverage
// bug fixed (kchunk 224 -> 232; 8*224=1792 < K=1800 dropped 8 k-elems).

namespace {

constexpr int S = 49, B = 64, DENC = 512, DD = 1800, DE = 512, V = 10000, T = 20;
constexpr int KC = DD + DE + DENC;   // 2824
constexpr int G4 = 4 * DD;           // 7200
constexpr int KCP = 2848;            // KC padded to %32
constexpr int DDP = 1824;            // DD padded to %32

typedef __attribute__((ext_vector_type(8))) short short8;
typedef __attribute__((ext_vector_type(4))) float f32x4;

__device__ inline float sigf(float x) { return 1.f / (1.f + expf(-x)); }

__device__ inline ushort f2bf_rne(float x) {
  unsigned u = __float_as_uint(x);
  unsigned r = (u + 0x7FFFu + ((u >> 16) & 1u)) >> 16;
  return (ushort)r;
}
__device__ inline void split1(float x, ushort& h, ushort& l) {
  h = f2bf_rne(x);
  float hf = __uint_as_float(((unsigned)h) << 16);
  l = f2bf_rne(x - hf);
}
__device__ inline void split8(float4 a, float4 b, short8& hi, short8& lo) {
  float v[8] = {a.x, a.y, a.z, a.w, b.x, b.y, b.z, b.w};
#pragma unroll
  for (int i = 0; i < 8; ++i) {
    ushort h, l; split1(v[i], h, l);
    hi[i] = (short)h; lo[i] = (short)l;
  }
}

// ---------------- h_avg = mean_s h[s,b,:] ----------------
__global__ __launch_bounds__(256) void hmean_kernel(const float* __restrict__ h,
                                                    float* __restrict__ h_avg) {
  int idx = blockIdx.x * 256 + threadIdx.x;
  if (idx >= B * DENC) return;
  float s = 0.f;
  for (int si = 0; si < S; ++si) s += h[(size_t)si * B * DENC + idx];
  h_avg[idx] = s * (1.0f / (float)S);
}

// ---------------- legacy fp32 GEMM (prologue h0/c0 only) ----------------
template <int ACT>
__global__ __launch_bounds__(256) void gemm_k(
    const float* __restrict__ A, int lda,
    const float* __restrict__ Wa, int ldwa, int Ka,
    const float* __restrict__ bias1,
    float* __restrict__ C, int ldc, int M, int N) {
  constexpr int BM = 64, BN = 32, BK = 64;
  __shared__ float As[BK][BM + 4];
  __shared__ float Ws[BK][BN + 4];
  const int tid = threadIdx.x;
  const int bm = blockIdx.y * BM, bn = blockIdx.x * BN;
  const int K = Ka;
  const int tm = tid & 15;
  const int tn = tid >> 4;
  const int f4 = tid & 15;
  const int lrow = tid >> 4;
  float acc[4][2] = {};
  for (int k0 = 0; k0 < K; k0 += BK) {
#pragma unroll
    for (int r = 0; r < 4; ++r) {
      int m = lrow + r * 16;
      int k = k0 + f4 * 4;
      float4 v = {0.f, 0.f, 0.f, 0.f};
      if (bm + m < M && k < K) v = *(const float4*)(A + (size_t)(bm + m) * lda + k);
      As[f4 * 4 + 0][m] = v.x; As[f4 * 4 + 1][m] = v.y;
      As[f4 * 4 + 2][m] = v.z; As[f4 * 4 + 3][m] = v.w;
    }
#pragma unroll
    for (int r = 0; r < 2; ++r) {
      int n = lrow + r * 16;
      int gn = bn + n;
      int kg = k0 + f4 * 4;
      float4 v = {0.f, 0.f, 0.f, 0.f};
      if (gn < N && kg < K) v = *(const float4*)(Wa + (size_t)gn * ldwa + kg);
      Ws[f4 * 4 + 0][n] = v.x; Ws[f4 * 4 + 1][n] = v.y;
      Ws[f4 * 4 + 2][n] = v.z; Ws[f4 * 4 + 3][n] = v.w;
    }
    __syncthreads();
#pragma unroll
    for (int kk = 0; kk < BK; ++kk) {
      float a0 = As[kk][tm * 4 + 0], a1 = As[kk][tm * 4 + 1];
      float a2 = As[kk][tm * 4 + 2], a3 = As[kk][tm * 4 + 3];
      float b0 = Ws[kk][tn * 2 + 0], b1 = Ws[kk][tn * 2 + 1];
      acc[0][0] += a0 * b0; acc[0][1] += a0 * b1;
      acc[1][0] += a1 * b0; acc[1][1] += a1 * b1;
      acc[2][0] += a2 * b0; acc[2][1] += a2 * b1;
      acc[3][0] += a3 * b0; acc[3][1] += a3 * b1;
    }
    __syncthreads();
  }
#pragma unroll
  for (int j = 0; j < 2; ++j) {
    int n = bn + tn * 2 + j;
    if (n >= N) continue;
    float bv = bias1 ? bias1[n] : 0.f;
#pragma unroll
    for (int i = 0; i < 4; ++i) {
      int m = bm + tm * 4 + i;
      if (m >= M) continue;
      float v = acc[i][j] + bv;
      if (ACT == 1) v = fmaxf(v, 0.f);
      C[(size_t)m * ldc + n] = v;
    }
  }
}

// ---------------- MFMA bf16x3 GEMM v2: software-pipelined ----------------
// C[m,n] = sum_k A[m,k]*W[n,k]. A pre-split bf16 hi/lo, zero-padded to ldap.
// W fp32 rows: [Wa[n][0:Ka] | Wb[n][..]], split in-register. Depth-1 prefetch.
// Caller must ensure gridDim.z * kchunk >= K and kchunk % 8 == 0.
__global__ __launch_bounds__(256) void mfma_gemm2(
    const ushort* __restrict__ Ahi, const ushort* __restrict__ Alo, int ldap,
    const float* __restrict__ Wa, int ldwa, int Ka,
    const float* __restrict__ Wb, int ldwb,
    float* __restrict__ P, int M, int N, int K, int kchunk) {
  const int lane = threadIdx.x & 63;
  const int wv = threadIdx.x >> 6;
  const int bn = blockIdx.x * 64 + wv * 16;
  const int bm = blockIdx.y * 64;
  const int z = blockIdx.z;
  const int row = lane & 15;
  const int kg = (lane >> 4) * 8;
  const int k_begin = z * kchunk;
  const int k_end = min(K, k_begin + kchunk);
  const int n = bn + row;
  const int nc = (n < N) ? n : (N - 1);

  const ushort* pa_hi = Ahi + (size_t)(bm + row) * ldap + kg;
  const ushort* pa_lo = Alo + (size_t)(bm + row) * ldap + kg;
  const float* wra = Wa + (size_t)nc * ldwa;
  const float* wrb = Wb + (size_t)nc * ldwb;

  f32x4 acc[4] = {};

  auto loadW = [&](int kk, float4& w0, float4& w1) {
    int k = kk + kg;
    const float* wp = (k < Ka) ? (wra + k) : (wrb + (k - Ka));
    w0 = *(const float4*)wp;
    w1 = *(const float4*)(wp + 4);
  };
  auto loadA = [&](int kk, short8* ah, short8* al) {
#pragma unroll
    for (int ms = 0; ms < 4; ++ms) {
      ah[ms] = *(const short8*)(pa_hi + (size_t)(ms * 16) * ldap + kk);
      al[ms] = *(const short8*)(pa_lo + (size_t)(ms * 16) * ldap + kk);
    }
  };

  const int nfull = (k_end > k_begin) ? ((k_end - k_begin) >> 5) : 0;
  float4 cw0, cw1;
  short8 cah[4], cal[4];

  if (nfull > 0) {
    loadW(k_begin, cw0, cw1);
    loadA(k_begin, cah, cal);
  }
  for (int it = 0; it < nfull; ++it) {
    const bool more = (it + 1 < nfull);
    float4 nw0, nw1;
    short8 nah[4], nal[4];
    if (more) {
      int kn = k_begin + (it + 1) * 32;
      loadW(kn, nw0, nw1);
      loadA(kn, nah, nal);
    }
    short8 wh, wl;
    split8(cw0, cw1, wh, wl);
#pragma unroll
    for (int ms = 0; ms < 4; ++ms) {
      acc[ms] = __builtin_amdgcn_mfma_f32_16x16x32_bf16(cah[ms], wh, acc[ms], 0, 0, 0);
      acc[ms] = __builtin_amdgcn_mfma_f32_16x16x32_bf16(cal[ms], wh, acc[ms], 0, 0, 0);
      acc[ms] = __builtin_amdgcn_mfma_f32_16x16x32_bf16(cah[ms], wl, acc[ms], 0, 0, 0);
    }
    if (more) {
      cw0 = nw0; cw1 = nw1;
#pragma unroll
      for (int ms = 0; ms < 4; ++ms) { cah[ms] = nah[ms]; cal[ms] = nal[ms]; }
    }
  }
  // tail: rem in {8,16,24}; A padding (zeros beyond K) nulls unguarded lanes
  const int ktail = k_begin + nfull * 32;
  if (ktail < k_end) {
    int rem = k_end - ktail;
    short8 wh = {}, wl = {};
    if (kg < rem) {
      float4 w0, w1;
      loadW(ktail, w0, w1);
      split8(w0, w1, wh, wl);
    }
    short8 tah[4], tal[4];
    loadA(ktail, tah, tal);
#pragma unroll
    for (int ms = 0; ms < 4; ++ms) {
      acc[ms] = __builtin_amdgcn_mfma_f32_16x16x32_bf16(tah[ms], wh, acc[ms], 0, 0, 0);
      acc[ms] = __builtin_amdgcn_mfma_f32_16x16x32_bf16(tal[ms], wh, acc[ms], 0, 0, 0);
      acc[ms] = __builtin_amdgcn_mfma_f32_16x16x32_bf16(tah[ms], wl, acc[ms], 0, 0, 0);
    }
  }

  if (n >= N) return;
  float* Pz = P + (size_t)z * ((size_t)M * N);
#pragma unroll
  for (int ms = 0; ms < 4; ++ms) {
    int r0 = bm + ms * 16 + (lane >> 4) * 4;
#pragma unroll
    for (int r = 0; r < 4; ++r) {
      Pz[(size_t)(r0 + r) * N + n] = acc[ms][r];
    }
  }
}

// ---------------- reduce over split-K partials (+bias) ----------------
template <int ACT>
__global__ __launch_bounds__(256) void reduce_k(const float* __restrict__ P, int nz,
                                                int total4, size_t MN, int N,
                                                const float* __restrict__ bias,
                                                float* __restrict__ C) {
  int i4 = blockIdx.x * 256 + threadIdx.x;
  if (i4 >= total4) return;
  size_t idx = (size_t)i4 * 4;
  float4 s = *(const float4*)(P + idx);
  for (int zz = 1; zz < nz; ++zz) {
    float4 t = *(const float4*)(P + (size_t)zz * MN + idx);
    s.x += t.x; s.y += t.y; s.z += t.z; s.w += t.w;
  }
  if (bias) {
    int nn = (int)(idx % (size_t)N);
    s.x += bias[nn]; s.y += bias[nn + 1]; s.z += bias[nn + 2]; s.w += bias[nn + 3];
  }
  if (ACT == 1) {
    s.x = fmaxf(s.x, 0.f); s.y = fmaxf(s.y, 0.f);
    s.z = fmaxf(s.z, 0.f); s.w = fmaxf(s.w, 0.f);
  }
  *(float4*)(C + idx) = s;
}

// ---------------- split fp32 rows -> bf16 hi/lo with zero pad ----------------
__global__ __launch_bounds__(256) void split_pad(const float* __restrict__ src, int K,
                                                 int KP, int rows,
                                                 ushort* __restrict__ hi,
                                                 ushort* __restrict__ lo) {
  int idx = blockIdx.x * 256 + threadIdx.x;
  if (idx >= rows * KP) return;
  int r = idx / KP, k = idx % KP;
  ushort h = 0, l = 0;
  if (k < K) split1(src[(size_t)r * K + k], h, l);
  hi[idx] = h; lo[idx] = l;
}

// ---------------- u[s,b] = relu(Q[b,:] + Hproj[s,b,:]) . w2 + b2 ----------------
__global__ __launch_bounds__(256) void attn_u_kernel(const float* __restrict__ Q,
                                                     const float* __restrict__ Hproj,
                                                     const float* __restrict__ w2,
                                                     const float* __restrict__ b2,
                                                     float* __restrict__ u) {
  int s = blockIdx.x, b = blockIdx.y;
  const float4* q4 = (const float4*)(Q + (size_t)b * DD);
  const float4* h4 = (const float4*)(Hproj + ((size_t)s * B + b) * DD);
  const float4* w4 = (const float4*)w2;
  float acc = 0.f;
  for (int i = threadIdx.x; i < DD / 4; i += 256) {
    float4 q = q4[i], hh = h4[i], w = w4[i];
    acc += fmaxf(q.x + hh.x, 0.f) * w.x + fmaxf(q.y + hh.y, 0.f) * w.y +
           fmaxf(q.z + hh.z, 0.f) * w.z + fmaxf(q.w + hh.w, 0.f) * w.w;
  }
  for (int off = 32; off; off >>= 1) acc += __shfl_xor(acc, off);
  __shared__ float red[4];
  if ((threadIdx.x & 63) == 0) red[threadIdx.x >> 6] = acc;
  __syncthreads();
  if (threadIdx.x == 0) u[s * B + b] = red[0] + red[1] + red[2] + red[3] + b2[0];
}

// ---------------- per-(b,slice): softmax, beta; slice of ctx + packing ----------------
__global__ __launch_bounds__(256) void softmax_ctx_pack(
    const float* __restrict__ u, const float* __restrict__ h,
    const float* __restrict__ ht, const float* __restrict__ beta_w,
    const float* __restrict__ beta_b, const float* __restrict__ emb,
    const int* __restrict__ Et, const int* __restrict__ prev_tok,
    ushort* __restrict__ xcat_hi, ushort* __restrict__ xcat_lo,
    ushort* __restrict__ cat2_hi, ushort* __restrict__ cat2_lo) {
  int b = blockIdx.x, slice = blockIdx.y, tid = threadIdx.x;
  __shared__ float a_sh[S];
  __shared__ float red[4];
  float uv = (tid < S) ? u[tid * B + b] : -INFINITY;
  float m = uv;
  for (int off = 32; off; off >>= 1) m = fmaxf(m, __shfl_xor(m, off));
  if ((tid & 63) == 0) red[tid >> 6] = m;
  __syncthreads();
  m = fmaxf(fmaxf(red[0], red[1]), fmaxf(red[2], red[3]));
  float e = (tid < S) ? expf(uv - m) : 0.f;
  float ssum = e;
  for (int off = 32; off; off >>= 1) ssum += __shfl_xor(ssum, off);
  __syncthreads();
  if ((tid & 63) == 0) red[tid >> 6] = ssum;
  __syncthreads();
  ssum = red[0] + red[1] + red[2] + red[3];
  if (tid < S) a_sh[tid] = e / ssum;
  float acc = 0.f;
  {
    const float4* h4 = (const float4*)(ht + (size_t)b * DD);
    const float4* w4 = (const float4*)beta_w;
    for (int i = tid; i < DD / 4; i += 256) {
      float4 x = h4[i], w = w4[i];
      acc += x.x * w.x + x.y * w.y + x.z * w.z + x.w * w.w;
    }
  }
  for (int off = 32; off; off >>= 1) acc += __shfl_xor(acc, off);
  __syncthreads();
  if ((tid & 63) == 0) red[tid >> 6] = acc;
  __syncthreads();
  float beta = sigf(red[0] + red[1] + red[2] + red[3] + beta_b[0]);

  const size_t xb = (size_t)b * KCP;
  for (int e0 = slice * 128 + tid; e0 < slice * 128 + 128; e0 += 256) {
    float c = 0.f;
    for (int si = 0; si < S; ++si) c += a_sh[si] * h[((size_t)si * B + b) * DENC + e0];
    c *= beta;
    ushort hh, ll; split1(c, hh, ll);
    xcat_hi[xb + DE + e0] = hh;      xcat_lo[xb + DE + e0] = ll;
    cat2_hi[xb + DD + DE + e0] = hh; cat2_lo[xb + DD + DE + e0] = ll;
  }
  int et = Et[b];
  int pt = prev_tok[b];
  for (int e0 = slice * 128 + tid; e0 < slice * 128 + 128; e0 += 256) {
    ushort hh, ll;
    split1(emb[(size_t)et * DE + e0], hh, ll);
    xcat_hi[xb + e0] = hh; xcat_lo[xb + e0] = ll;
    split1(emb[(size_t)pt * DE + e0], hh, ll);
    cat2_hi[xb + DD + e0] = hh; cat2_lo[xb + DD + e0] = ll;
  }
  for (int j = slice * 450 + tid; j < slice * 450 + 450; j += 256) {
    ushort hh, ll; split1(ht[(size_t)b * DD + j], hh, ll);
    xcat_hi[xb + DE + DENC + j] = hh; xcat_lo[xb + DE + DENC + j] = ll;
  }
  if (slice == 3 && tid < KCP - KC) {
    xcat_hi[xb + KC + tid] = 0; xcat_lo[xb + KC + tid] = 0;
    cat2_hi[xb + KC + tid] = 0; cat2_lo[xb + KC + tid] = 0;
  }
}

// ---------------- LSTM: reduce gates partials + update + bf16 splits ----------------
__global__ __launch_bounds__(256) void lstm_fused(
    const float* __restrict__ P, int nz, const float* __restrict__ b_ih,
    const float* __restrict__ b_hh, float* __restrict__ ct, float* __restrict__ ht,
    ushort* __restrict__ cat2_hi, ushort* __restrict__ cat2_lo,
    ushort* __restrict__ ht_hi, ushort* __restrict__ ht_lo) {
  int idx = blockIdx.x * 256 + threadIdx.x;
  if (idx >= B * DD) return;
  int b = idx / DD, d = idx % DD;
  const size_t MN = (size_t)B * G4;
  float g0 = 0.f, g1 = 0.f, g2 = 0.f, g3 = 0.f;
  for (int zz = 0; zz < nz; ++zz) {
    const float* g = P + (size_t)zz * MN + (size_t)b * G4;
    g0 += g[d]; g1 += g[DD + d]; g2 += g[2 * DD + d]; g3 += g[3 * DD + d];
  }
  g0 += b_ih[d] + b_hh[d];
  g1 += b_ih[DD + d] + b_hh[DD + d];
  g2 += b_ih[2 * DD + d] + b_hh[2 * DD + d];
  g3 += b_ih[3 * DD + d] + b_hh[3 * DD + d];
  float c = sigf(g1) * ct[idx] + sigf(g0) * tanhf(g2);
  float hn = sigf(g3) * tanhf(c);
  ct[idx] = c;
  ht[idx] = hn;
  ushort hh, ll; split1(hn, hh, ll);
  cat2_hi[(size_t)b * KCP + d] = hh; cat2_lo[(size_t)b * KCP + d] = ll;
  ht_hi[(size_t)b * DDP + d] = hh;   ht_lo[(size_t)b * DDP + d] = ll;
  if (d < DDP - DD) {
    ht_hi[(size_t)b * DDP + DD + d] = 0; ht_lo[(size_t)b * DDP + DD + d] = 0;
  }
}

// ---------------- per-b argmax over V ----------------
__global__ __launch_bounds__(256) void argmax_kernel(const float* __restrict__ logits,
                                                     int* __restrict__ tok) {
  int b = blockIdx.x;
  const float* row = logits + (size_t)b * V;
  float best = -INFINITY;
  int bi = 0x7fffffff;
  for (int v = threadIdx.x; v < V; v += 256) {
    float x = row[v];
    if (x > best) { best = x; bi = v; }
  }
  for (int off = 32; off; off >>= 1) {
    float ov = __shfl_xor(best, off);
    int oi = __shfl_xor(bi, off);
    if (ov > best || (ov == best && oi < bi)) { best = ov; bi = oi; }
  }
  __shared__ float bv[4];
  __shared__ int bix[4];
  if ((threadIdx.x & 63) == 0) { bv[threadIdx.x >> 6] = best; bix[threadIdx.x >> 6] = bi; }
  __syncthreads();
  if (threadIdx.x == 0) {
    for (int w = 1; w < 4; ++w)
      if (bv[w] > best || (bv[w] == best && bix[w] < bi)) { best = bv[w]; bi = bix[w]; }
    tok[b] = bi;
  }
}

__global__ void zero_tok(int* tok) { if (threadIdx.x < B) tok[threadIdx.x] = 0; }

// ws layout (float offsets) — total ~53 MB (known-safe)
constexpr size_t OFF_HAVG  = 0;                       // 64*512
constexpr size_t OFF_TMP   = OFF_HAVG + 32768;        // 64*1800
constexpr size_t OFF_HT    = OFF_TMP + 115200;
constexpr size_t OFF_CT    = OFF_HT + 115200;
constexpr size_t OFF_HPROJ = OFF_CT + 115200;         // 3136*1800
constexpr size_t OFF_Q     = OFF_HPROJ + 5644800;
constexpr size_t OFF_U     = OFF_Q + 115200;
constexpr size_t OFF_TOK   = OFF_U + 3200;
constexpr size_t OFF_PBUF  = OFF_TOK + 128;           // 8*64*10000 = 5,120,000
constexpr size_t OFF_BF    = OFF_PBUF + 5120000;      // ushort area

// ushort offsets within bf area
constexpr size_t U_HT_HI   = 0;                            // 64*1824
constexpr size_t U_HT_LO   = U_HT_HI + (size_t)B * DDP;
constexpr size_t U_XC_HI   = U_HT_LO + (size_t)B * DDP;    // 64*2848
constexpr size_t U_XC_LO   = U_XC_HI + (size_t)B * KCP;
constexpr size_t U_C2_HI   = U_XC_LO + (size_t)B * KCP;
constexpr size_t U_C2_LO   = U_C2_HI + (size_t)B * KCP;
constexpr size_t U_H_HI    = U_C2_LO + (size_t)B * KCP;    // 3136*512
constexpr size_t U_H_LO    = U_H_HI + (size_t)(S * B) * DENC;

}  // namespace

extern "C" void kernel_launch(void* const* d_in, const int* in_sizes, int n_in,
                              void* d_out, int out_size, void* d_ws, size_t ws_size,
                              hipStream_t stream) {
  const float* h       = (const float*)d_in[0];
  const int*   E       = (const int*)d_in[1];
  const float* emb     = (const float*)d_in[2];
  const float* attn_W1 = (const float*)d_in[3];
  const float* attn_b1 = (const float*)d_in[4];
  const float* attn_w2 = (const float*)d_in[5];
  const float* attn_b2 = (const float*)d_in[6];
  const float* beta_w  = (const float*)d_in[7];
  const float* beta_b  = (const float*)d_in[8];
  const float* W_ih    = (const float*)d_in[9];
  const float* W_hh    = (const float*)d_in[10];
  const float* b_ih    = (const float*)d_in[11];
  const float* b_hh    = (const float*)d_in[12];
  const float* out_W   = (const float*)d_in[13];
  const float* out_b   = (const float*)d_in[14];
  const float* ih_W1   = (const float*)d_in[15];
  const float* ih_b1   = (const float*)d_in[16];
  const float* ih_W2   = (const float*)d_in[17];
  const float* ih_b2   = (const float*)d_in[18];
  const float* ic_W1   = (const float*)d_in[19];
  const float* ic_b1   = (const float*)d_in[20];
  const float* ic_W2   = (const float*)d_in[21];
  const float* ic_b2   = (const float*)d_in[22];

  float* ws    = (float*)d_ws;
  float* havg  = ws + OFF_HAVG;
  float* tmp   = ws + OFF_TMP;
  float* ht    = ws + OFF_HT;
  float* ct    = ws + OFF_CT;
  float* Hproj = ws + OFF_HPROJ;
  float* Q     = ws + OFF_Q;
  float* u     = ws + OFF_U;
  int*   tok   = (int*)(ws + OFF_TOK);
  float* PBUF  = ws + OFF_PBUF;
  ushort* bfb  = (ushort*)(ws + OFF_BF);
  ushort* ht_hi = bfb + U_HT_HI;
  ushort* ht_lo = bfb + U_HT_LO;
  ushort* xc_hi = bfb + U_XC_HI;
  ushort* xc_lo = bfb + U_XC_LO;
  ushort* c2_hi = bfb + U_C2_HI;
  ushort* c2_lo = bfb + U_C2_LO;
  ushort* h_hi  = bfb + U_H_HI;
  ushort* h_lo  = bfb + U_H_LO;
  float* out   = (float*)d_out;

  auto cdiv = [](int a, int b) { return (a + b - 1) / b; };

  // ---- prologue ----
  hmean_kernel<<<cdiv(B * DENC, 256), 256, 0, stream>>>(h, havg);
  gemm_k<1><<<dim3(cdiv(DD, 32), 1), 256, 0, stream>>>(havg, DENC, ih_W1, DENC, DENC,
      ih_b1, tmp, DD, B, DD);
  gemm_k<0><<<dim3(cdiv(DD, 32), 1), 256, 0, stream>>>(tmp, DD, ih_W2, DD, DD,
      ih_b2, ht, DD, B, DD);
  gemm_k<1><<<dim3(cdiv(DD, 32), 1), 256, 0, stream>>>(havg, DENC, ic_W1, DENC, DENC,
      ic_b1, tmp, DD, B, DD);
  gemm_k<0><<<dim3(cdiv(DD, 32), 1), 256, 0, stream>>>(tmp, DD, ic_W2, DD, DD,
      ic_b2, ct, DD, B, DD);
  split_pad<<<cdiv(B * DDP, 256), 256, 0, stream>>>(ht, DD, DDP, B, ht_hi, ht_lo);
  split_pad<<<cdiv(S * B * DENC, 256), 256, 0, stream>>>(h, DENC, DENC, S * B, h_hi, h_lo);
  // Hproj = h @ W1h.T + attn_b1  (z=1, K=512)
  mfma_gemm2<<<dim3(cdiv(DD, 64), S * B / 64, 1), 256, 0, stream>>>(
      h_hi, h_lo, DENC, attn_W1 + DD, DD + DENC, DENC, attn_W1 + DD, DD + DENC,
      Hproj, S * B, DD, DENC, DENC);
  reduce_k<0><<<cdiv(S * B * DD / 4, 256), 256, 0, stream>>>(
      Hproj, 1, S * B * DD / 4, (size_t)S * B * DD, DD, attn_b1, Hproj);
  zero_tok<<<1, 64, 0, stream>>>(tok);

  // ---- decode steps ----
  for (int t = 0; t < T - 1; ++t) {
    // Q = ht @ W1q.T  (z=8, kchunk=232: 8*232=1856 >= 1800; kchunk%8==0)
    mfma_gemm2<<<dim3(cdiv(DD, 64), 1, 8), 256, 0, stream>>>(
        ht_hi, ht_lo, DDP, attn_W1, DD + DENC, DD, attn_W1, DD + DENC,
        PBUF, B, DD, DD, 232);
    reduce_k<0><<<cdiv(B * DD / 4, 256), 256, 0, stream>>>(
        PBUF, 8, B * DD / 4, (size_t)B * DD, DD, nullptr, Q);
    attn_u_kernel<<<dim3(S, B), 256, 0, stream>>>(Q, Hproj, attn_w2, attn_b2, u);
    softmax_ctx_pack<<<dim3(B, 4), 256, 0, stream>>>(u, h, ht, beta_w, beta_b, emb,
        E + (size_t)t * B, tok, xc_hi, xc_lo, c2_hi, c2_lo);
    // gates = xcat @ [W_ih | W_hh].T  (z=8, kchunk=384: 3072 >= 2824)
    mfma_gemm2<<<dim3(cdiv(G4, 64), 1, 8), 256, 0, stream>>>(
        xc_hi, xc_lo, KCP, W_ih, DE + DENC, DE + DENC, W_hh, DD,
        PBUF, B, G4, KC, 384);
    lstm_fused<<<cdiv(B * DD, 256), 256, 0, stream>>>(
        PBUF, 8, b_ih, b_hh, ct, ht, c2_hi, c2_lo, ht_hi, ht_lo);
    // logits = cat2 @ out_W.T  (z=6, kchunk=480: 2880 >= 2824) -> d_out[t]
    float* logits_t = out + (size_t)t * B * V;
    mfma_gemm2<<<dim3(cdiv(V, 64), 1, 6), 256, 0, stream>>>(
        c2_hi, c2_lo, KCP, out_W, KC, KC, out_W, KC,
        PBUF, B, V, KC, 480);
    reduce_k<0><<<cdiv(B * V / 4, 256), 256, 0, stream>>>(
        PBUF, 6, B * V / 4, (size_t)B * V, V, out_b, logits_t);
    argmax_kernel<<<B, 256, 0, stream>>>(logits_t, tok);
  }
  (void)in_sizes; (void)n_in; (void)out_size; (void)ws_size;
}

// Round 6
// 2761.976 us; speedup vs baseline: 1.2532x; 1.2532x over previous
//
#include <hip/hip_runtime.h>
#include <hip/hip_bf16.h>
#include <cmath>

// EncoderDecoder: S=49,B=64,DENC=512,DD=1800,DE=512,V=10000,T=20
// Round 6: prologue fp32 GEMMs -> MFMA path; mfma_gemm3 = 32 n-cols/wave
// (24 MFMA / 12 loads per iter), depth-1 prefetch; PBUF moved last with
// ws-gated z=10 for logits (fallback z=8 = known-safe footprint).

namespace {

constexpr int S = 49, B = 64, DENC = 512, DD = 1800, DE = 512, V = 10000, T = 20;
constexpr int KC = DD + DE + DENC;   // 2824
constexpr int G4 = 4 * DD;           // 7200
constexpr int KCP = 2848;            // KC padded to %32
constexpr int DDP = 1824;            // DD padded to %32

typedef __attribute__((ext_vector_type(8))) short short8;
typedef __attribute__((ext_vector_type(4))) float f32x4;

__device__ inline float sigf(float x) { return 1.f / (1.f + expf(-x)); }

__device__ inline ushort f2bf_rne(float x) {
  unsigned u = __float_as_uint(x);
  unsigned r = (u + 0x7FFFu + ((u >> 16) & 1u)) >> 16;
  return (ushort)r;
}
__device__ inline void split1(float x, ushort& h, ushort& l) {
  h = f2bf_rne(x);
  float hf = __uint_as_float(((unsigned)h) << 16);
  l = f2bf_rne(x - hf);
}
__device__ inline void split8(float4 a, float4 b, short8& hi, short8& lo) {
  float v[8] = {a.x, a.y, a.z, a.w, b.x, b.y, b.z, b.w};
#pragma unroll
  for (int i = 0; i < 8; ++i) {
    ushort h, l; split1(v[i], h, l);
    hi[i] = (short)h; lo[i] = (short)l;
  }
}

// ---------------- h_avg = mean_s h[s,b,:] ----------------
__global__ __launch_bounds__(256) void hmean_kernel(const float* __restrict__ h,
                                                    float* __restrict__ h_avg) {
  int idx = blockIdx.x * 256 + threadIdx.x;
  if (idx >= B * DENC) return;
  float s = 0.f;
  for (int si = 0; si < S; ++si) s += h[(size_t)si * B * DENC + idx];
  h_avg[idx] = s * (1.0f / (float)S);
}

// ---------------- MFMA bf16x3 GEMM v3: 2 n-tiles/wave, depth-1 prefetch ----
// C[m,n] = sum_k A[m,k]*W[n,k]. A pre-split bf16 hi/lo, zero-padded to ldap
// (>= roundup32(K), %32). W fp32 rows [Wa[n][0:Ka] | Wb[n][...]], split
// in-register. Wave: 32 n-cols (2 tiles), 64 m-rows. kchunk%8==0;
// grid.z*kchunk >= K. Writes fp32 partials P[z][M][N]. M%64==0.
__global__ __launch_bounds__(256) void mfma_gemm3(
    const ushort* __restrict__ Ahi, const ushort* __restrict__ Alo, int ldap,
    const float* __restrict__ Wa, int ldwa, int Ka,
    const float* __restrict__ Wb, int ldwb,
    float* __restrict__ P, int M, int N, int K, int kchunk) {
  const int lane = threadIdx.x & 63;
  const int wv = threadIdx.x >> 6;
  const int nbase = blockIdx.x * 128 + wv * 32;
  const int bm = blockIdx.y * 64;
  const int z = blockIdx.z;
  const int row = lane & 15;
  const int kg = (lane >> 4) * 8;
  const int k_begin = z * kchunk;
  const int k_end = min(K, k_begin + kchunk);

  const int n0 = nbase + row, n1 = n0 + 16;
  const int nc0 = (n0 < N) ? n0 : (N - 1);
  const int nc1 = (n1 < N) ? n1 : (N - 1);

  const ushort* pa_hi = Ahi + (size_t)(bm + row) * ldap + kg;
  const ushort* pa_lo = Alo + (size_t)(bm + row) * ldap + kg;

  f32x4 acc[2][4] = {};

  auto wptr = [&](int nc, int k) -> const float* {
    return (k < Ka) ? (Wa + (size_t)nc * ldwa + k)
                    : (Wb + (size_t)nc * ldwb + (k - Ka));
  };
  auto loadW2 = [&](int kk, float4* w) {
    const float* p0 = wptr(nc0, kk + kg);
    const float* p1 = wptr(nc1, kk + kg);
    w[0] = *(const float4*)p0; w[1] = *(const float4*)(p0 + 4);
    w[2] = *(const float4*)p1; w[3] = *(const float4*)(p1 + 4);
  };
  auto loadA = [&](int kk, short8* ah, short8* al) {
#pragma unroll
    for (int ms = 0; ms < 4; ++ms) {
      ah[ms] = *(const short8*)(pa_hi + (size_t)(ms * 16) * ldap + kk);
      al[ms] = *(const short8*)(pa_lo + (size_t)(ms * 16) * ldap + kk);
    }
  };

  const int nfull = (k_end > k_begin) ? ((k_end - k_begin) >> 5) : 0;
  float4 cw[4];
  short8 cah[4], cal[4];
  if (nfull) { loadW2(k_begin, cw); loadA(k_begin, cah, cal); }
  for (int it = 0; it < nfull; ++it) {
    const bool more = (it + 1 < nfull);
    float4 nw[4];
    short8 nah[4], nal[4];
    if (more) {
      int kn = k_begin + (it + 1) * 32;
      loadW2(kn, nw);
      loadA(kn, nah, nal);
    }
    short8 wh0, wl0, wh1, wl1;
    split8(cw[0], cw[1], wh0, wl0);
    split8(cw[2], cw[3], wh1, wl1);
#pragma unroll
    for (int ms = 0; ms < 4; ++ms) {
      acc[0][ms] = __builtin_amdgcn_mfma_f32_16x16x32_bf16(cah[ms], wh0, acc[0][ms], 0, 0, 0);
      acc[0][ms] = __builtin_amdgcn_mfma_f32_16x16x32_bf16(cal[ms], wh0, acc[0][ms], 0, 0, 0);
      acc[0][ms] = __builtin_amdgcn_mfma_f32_16x16x32_bf16(cah[ms], wl0, acc[0][ms], 0, 0, 0);
      acc[1][ms] = __builtin_amdgcn_mfma_f32_16x16x32_bf16(cah[ms], wh1, acc[1][ms], 0, 0, 0);
      acc[1][ms] = __builtin_amdgcn_mfma_f32_16x16x32_bf16(cal[ms], wh1, acc[1][ms], 0, 0, 0);
      acc[1][ms] = __builtin_amdgcn_mfma_f32_16x16x32_bf16(cah[ms], wl1, acc[1][ms], 0, 0, 0);
    }
    if (more) {
#pragma unroll
      for (int q = 0; q < 4; ++q) cw[q] = nw[q];
#pragma unroll
      for (int ms = 0; ms < 4; ++ms) { cah[ms] = nah[ms]; cal[ms] = nal[ms]; }
    }
  }
  // tail: rem in {8,16,24}; A zero-padding nulls unguarded k
  const int ktail = k_begin + nfull * 32;
  if (ktail < k_end) {
    int rem = k_end - ktail;
    short8 wh0 = {}, wl0 = {}, wh1 = {}, wl1 = {};
    if (kg < rem) {
      float4 w[4];
      loadW2(ktail, w);
      split8(w[0], w[1], wh0, wl0);
      split8(w[2], w[3], wh1, wl1);
    }
    short8 tah[4], tal[4];
    loadA(ktail, tah, tal);
#pragma unroll
    for (int ms = 0; ms < 4; ++ms) {
      acc[0][ms] = __builtin_amdgcn_mfma_f32_16x16x32_bf16(tah[ms], wh0, acc[0][ms], 0, 0, 0);
      acc[0][ms] = __builtin_amdgcn_mfma_f32_16x16x32_bf16(tal[ms], wh0, acc[0][ms], 0, 0, 0);
      acc[0][ms] = __builtin_amdgcn_mfma_f32_16x16x32_bf16(tah[ms], wl0, acc[0][ms], 0, 0, 0);
      acc[1][ms] = __builtin_amdgcn_mfma_f32_16x16x32_bf16(tah[ms], wh1, acc[1][ms], 0, 0, 0);
      acc[1][ms] = __builtin_amdgcn_mfma_f32_16x16x32_bf16(tal[ms], wh1, acc[1][ms], 0, 0, 0);
      acc[1][ms] = __builtin_amdgcn_mfma_f32_16x16x32_bf16(tah[ms], wl1, acc[1][ms], 0, 0, 0);
    }
  }

  float* Pz = P + (size_t)z * ((size_t)M * N);
#pragma unroll
  for (int j = 0; j < 2; ++j) {
    int n = nbase + j * 16 + row;
    if (n >= N) continue;
#pragma unroll
    for (int ms = 0; ms < 4; ++ms) {
      int r0 = bm + ms * 16 + (lane >> 4) * 4;
#pragma unroll
      for (int r = 0; r < 4; ++r) {
        Pz[(size_t)(r0 + r) * N + n] = acc[j][ms][r];
      }
    }
  }
}

// ---------------- reduce over split-K partials (+bias, +relu) ----------------
template <int ACT>
__global__ __launch_bounds__(256) void reduce_k(const float* __restrict__ P, int nz,
                                                int total4, size_t MN, int N,
                                                const float* __restrict__ bias,
                                                float* __restrict__ C) {
  int i4 = blockIdx.x * 256 + threadIdx.x;
  if (i4 >= total4) return;
  size_t idx = (size_t)i4 * 4;
  float4 s = *(const float4*)(P + idx);
  for (int zz = 1; zz < nz; ++zz) {
    float4 t = *(const float4*)(P + (size_t)zz * MN + idx);
    s.x += t.x; s.y += t.y; s.z += t.z; s.w += t.w;
  }
  if (bias) {
    int nn = (int)(idx % (size_t)N);
    s.x += bias[nn]; s.y += bias[nn + 1]; s.z += bias[nn + 2]; s.w += bias[nn + 3];
  }
  if (ACT == 1) {
    s.x = fmaxf(s.x, 0.f); s.y = fmaxf(s.y, 0.f);
    s.z = fmaxf(s.z, 0.f); s.w = fmaxf(s.w, 0.f);
  }
  *(float4*)(C + idx) = s;
}

// ---------------- split fp32 rows -> bf16 hi/lo with zero pad ----------------
__global__ __launch_bounds__(256) void split_pad(const float* __restrict__ src, int K,
                                                 int KP, int rows,
                                                 ushort* __restrict__ hi,
                                                 ushort* __restrict__ lo) {
  int idx = blockIdx.x * 256 + threadIdx.x;
  if (idx >= rows * KP) return;
  int r = idx / KP, k = idx % KP;
  ushort h = 0, l = 0;
  if (k < K) split1(src[(size_t)r * K + k], h, l);
  hi[idx] = h; lo[idx] = l;
}

// ---------------- u[s,b] = relu(Q[b,:] + Hproj[s,b,:]) . w2 + b2 ----------------
__global__ __launch_bounds__(256) void attn_u_kernel(const float* __restrict__ Q,
                                                     const float* __restrict__ Hproj,
                                                     const float* __restrict__ w2,
                                                     const float* __restrict__ b2,
                                                     float* __restrict__ u) {
  int s = blockIdx.x, b = blockIdx.y;
  const float4* q4 = (const float4*)(Q + (size_t)b * DD);
  const float4* h4 = (const float4*)(Hproj + ((size_t)s * B + b) * DD);
  const float4* w4 = (const float4*)w2;
  float acc = 0.f;
  for (int i = threadIdx.x; i < DD / 4; i += 256) {
    float4 q = q4[i], hh = h4[i], w = w4[i];
    acc += fmaxf(q.x + hh.x, 0.f) * w.x + fmaxf(q.y + hh.y, 0.f) * w.y +
           fmaxf(q.z + hh.z, 0.f) * w.z + fmaxf(q.w + hh.w, 0.f) * w.w;
  }
  for (int off = 32; off; off >>= 1) acc += __shfl_xor(acc, off);
  __shared__ float red[4];
  if ((threadIdx.x & 63) == 0) red[threadIdx.x >> 6] = acc;
  __syncthreads();
  if (threadIdx.x == 0) u[s * B + b] = red[0] + red[1] + red[2] + red[3] + b2[0];
}

// ---------------- per-(b,slice): softmax, beta; slice of ctx + packing ----------------
__global__ __launch_bounds__(256) void softmax_ctx_pack(
    const float* __restrict__ u, const float* __restrict__ h,
    const float* __restrict__ ht, const float* __restrict__ beta_w,
    const float* __restrict__ beta_b, const float* __restrict__ emb,
    const int* __restrict__ Et, const int* __restrict__ prev_tok,
    ushort* __restrict__ xcat_hi, ushort* __restrict__ xcat_lo,
    ushort* __restrict__ cat2_hi, ushort* __restrict__ cat2_lo) {
  int b = blockIdx.x, slice = blockIdx.y, tid = threadIdx.x;
  __shared__ float a_sh[S];
  __shared__ float red[4];
  float uv = (tid < S) ? u[tid * B + b] : -INFINITY;
  float m = uv;
  for (int off = 32; off; off >>= 1) m = fmaxf(m, __shfl_xor(m, off));
  if ((tid & 63) == 0) red[tid >> 6] = m;
  __syncthreads();
  m = fmaxf(fmaxf(red[0], red[1]), fmaxf(red[2], red[3]));
  float e = (tid < S) ? expf(uv - m) : 0.f;
  float ssum = e;
  for (int off = 32; off; off >>= 1) ssum += __shfl_xor(ssum, off);
  __syncthreads();
  if ((tid & 63) == 0) red[tid >> 6] = ssum;
  __syncthreads();
  ssum = red[0] + red[1] + red[2] + red[3];
  if (tid < S) a_sh[tid] = e / ssum;
  float acc = 0.f;
  {
    const float4* h4 = (const float4*)(ht + (size_t)b * DD);
    const float4* w4 = (const float4*)beta_w;
    for (int i = tid; i < DD / 4; i += 256) {
      float4 x = h4[i], w = w4[i];
      acc += x.x * w.x + x.y * w.y + x.z * w.z + x.w * w.w;
    }
  }
  for (int off = 32; off; off >>= 1) acc += __shfl_xor(acc, off);
  __syncthreads();
  if ((tid & 63) == 0) red[tid >> 6] = acc;
  __syncthreads();
  float beta = sigf(red[0] + red[1] + red[2] + red[3] + beta_b[0]);

  const size_t xb = (size_t)b * KCP;
  for (int e0 = slice * 128 + tid; e0 < slice * 128 + 128; e0 += 256) {
    float c = 0.f;
    for (int si = 0; si < S; ++si) c += a_sh[si] * h[((size_t)si * B + b) * DENC + e0];
    c *= beta;
    ushort hh, ll; split1(c, hh, ll);
    xcat_hi[xb + DE + e0] = hh;      xcat_lo[xb + DE + e0] = ll;
    cat2_hi[xb + DD + DE + e0] = hh; cat2_lo[xb + DD + DE + e0] = ll;
  }
  int et = Et[b];
  int pt = prev_tok[b];
  for (int e0 = slice * 128 + tid; e0 < slice * 128 + 128; e0 += 256) {
    ushort hh, ll;
    split1(emb[(size_t)et * DE + e0], hh, ll);
    xcat_hi[xb + e0] = hh; xcat_lo[xb + e0] = ll;
    split1(emb[(size_t)pt * DE + e0], hh, ll);
    cat2_hi[xb + DD + e0] = hh; cat2_lo[xb + DD + e0] = ll;
  }
  for (int j = slice * 450 + tid; j < slice * 450 + 450; j += 256) {
    ushort hh, ll; split1(ht[(size_t)b * DD + j], hh, ll);
    xcat_hi[xb + DE + DENC + j] = hh; xcat_lo[xb + DE + DENC + j] = ll;
  }
  if (slice == 3 && tid < KCP - KC) {
    xcat_hi[xb + KC + tid] = 0; xcat_lo[xb + KC + tid] = 0;
    cat2_hi[xb + KC + tid] = 0; cat2_lo[xb + KC + tid] = 0;
  }
}

// ---------------- LSTM: reduce gates partials + update + bf16 splits ----------------
__global__ __launch_bounds__(256) void lstm_fused(
    const float* __restrict__ P, int nz, const float* __restrict__ b_ih,
    const float* __restrict__ b_hh, float* __restrict__ ct, float* __restrict__ ht,
    ushort* __restrict__ cat2_hi, ushort* __restrict__ cat2_lo,
    ushort* __restrict__ ht_hi, ushort* __restrict__ ht_lo) {
  int idx = blockIdx.x * 256 + threadIdx.x;
  if (idx >= B * DD) return;
  int b = idx / DD, d = idx % DD;
  const size_t MN = (size_t)B * G4;
  float g0 = 0.f, g1 = 0.f, g2 = 0.f, g3 = 0.f;
  for (int zz = 0; zz < nz; ++zz) {
    const float* g = P + (size_t)zz * MN + (size_t)b * G4;
    g0 += g[d]; g1 += g[DD + d]; g2 += g[2 * DD + d]; g3 += g[3 * DD + d];
  }
  g0 += b_ih[d] + b_hh[d];
  g1 += b_ih[DD + d] + b_hh[DD + d];
  g2 += b_ih[2 * DD + d] + b_hh[2 * DD + d];
  g3 += b_ih[3 * DD + d] + b_hh[3 * DD + d];
  float c = sigf(g1) * ct[idx] + sigf(g0) * tanhf(g2);
  float hn = sigf(g3) * tanhf(c);
  ct[idx] = c;
  ht[idx] = hn;
  ushort hh, ll; split1(hn, hh, ll);
  cat2_hi[(size_t)b * KCP + d] = hh; cat2_lo[(size_t)b * KCP + d] = ll;
  ht_hi[(size_t)b * DDP + d] = hh;   ht_lo[(size_t)b * DDP + d] = ll;
  if (d < DDP - DD) {
    ht_hi[(size_t)b * DDP + DD + d] = 0; ht_lo[(size_t)b * DDP + DD + d] = 0;
  }
}

// ---------------- per-b argmax over V ----------------
__global__ __launch_bounds__(256) void argmax_kernel(const float* __restrict__ logits,
                                                     int* __restrict__ tok) {
  int b = blockIdx.x;
  const float* row = logits + (size_t)b * V;
  float best = -INFINITY;
  int bi = 0x7fffffff;
  for (int v = threadIdx.x; v < V; v += 256) {
    float x = row[v];
    if (x > best) { best = x; bi = v; }
  }
  for (int off = 32; off; off >>= 1) {
    float ov = __shfl_xor(best, off);
    int oi = __shfl_xor(bi, off);
    if (ov > best || (ov == best && oi < bi)) { best = ov; bi = oi; }
  }
  __shared__ float bv[4];
  __shared__ int bix[4];
  if ((threadIdx.x & 63) == 0) { bv[threadIdx.x >> 6] = best; bix[threadIdx.x >> 6] = bi; }
  __syncthreads();
  if (threadIdx.x == 0) {
    for (int w = 1; w < 4; ++w)
      if (bv[w] > best || (bv[w] == best && bix[w] < bi)) { best = bv[w]; bi = bix[w]; }
    tok[b] = bi;
  }
}

__global__ void zero_tok(int* tok) { if (threadIdx.x < B) tok[threadIdx.x] = 0; }

// ws layout: fixed fp32 region, then ushort region, then PBUF (extensible).
constexpr size_t OFF_HAVG  = 0;                       // 64*512
constexpr size_t OFF_TMP   = OFF_HAVG + 32768;        // 64*1800
constexpr size_t OFF_HT    = OFF_TMP + 115200;
constexpr size_t OFF_CT    = OFF_HT + 115200;
constexpr size_t OFF_HPROJ = OFF_CT + 115200;         // 3136*1800
constexpr size_t OFF_Q     = OFF_HPROJ + 5644800;
constexpr size_t OFF_U     = OFF_Q + 115200;
constexpr size_t OFF_TOK   = OFF_U + 3200;
constexpr size_t OFF_USH   = OFF_TOK + 128;           // ushort area (float offset)

// ushort offsets within ushort area
constexpr size_t U_HT_HI   = 0;                            // 64*1824
constexpr size_t U_HT_LO   = U_HT_HI + (size_t)B * DDP;
constexpr size_t U_XC_HI   = U_HT_LO + (size_t)B * DDP;    // 64*2848
constexpr size_t U_XC_LO   = U_XC_HI + (size_t)B * KCP;
constexpr size_t U_C2_HI   = U_XC_LO + (size_t)B * KCP;
constexpr size_t U_C2_LO   = U_C2_HI + (size_t)B * KCP;
constexpr size_t U_H_HI    = U_C2_LO + (size_t)B * KCP;    // 3136*512
constexpr size_t U_H_LO    = U_H_HI + (size_t)(S * B) * DENC;
constexpr size_t U_END     = U_H_LO + (size_t)(S * B) * DENC;  // 4,173,824

constexpr size_t OFF_PBUF  = OFF_USH + U_END / 2;     // 8,228,608 floats
constexpr size_t PBUF_Z8   = 8u * 64 * 10000;         // 5,120,000 floats
constexpr size_t PBUF_Z10  = 10u * 64 * 10000;        // 6,400,000 floats
constexpr size_t NEED_Z10  = (OFF_PBUF + PBUF_Z10) * 4;  // 58,514,432 B

}  // namespace

extern "C" void kernel_launch(void* const* d_in, const int* in_sizes, int n_in,
                              void* d_out, int out_size, void* d_ws, size_t ws_size,
                              hipStream_t stream) {
  const float* h       = (const float*)d_in[0];
  const int*   E       = (const int*)d_in[1];
  const float* emb     = (const float*)d_in[2];
  const float* attn_W1 = (const float*)d_in[3];
  const float* attn_b1 = (const float*)d_in[4];
  const float* attn_w2 = (const float*)d_in[5];
  const float* attn_b2 = (const float*)d_in[6];
  const float* beta_w  = (const float*)d_in[7];
  const float* beta_b  = (const float*)d_in[8];
  const float* W_ih    = (const float*)d_in[9];
  const float* W_hh    = (const float*)d_in[10];
  const float* b_ih    = (const float*)d_in[11];
  const float* b_hh    = (const float*)d_in[12];
  const float* out_W   = (const float*)d_in[13];
  const float* out_b   = (const float*)d_in[14];
  const float* ih_W1   = (const float*)d_in[15];
  const float* ih_b1   = (const float*)d_in[16];
  const float* ih_W2   = (const float*)d_in[17];
  const float* ih_b2   = (const float*)d_in[18];
  const float* ic_W1   = (const float*)d_in[19];
  const float* ic_b1   = (const float*)d_in[20];
  const float* ic_W2   = (const float*)d_in[21];
  const float* ic_b2   = (const float*)d_in[22];

  float* ws    = (float*)d_ws;
  float* havg  = ws + OFF_HAVG;
  float* tmp   = ws + OFF_TMP;
  float* ht    = ws + OFF_HT;
  float* ct    = ws + OFF_CT;
  float* Hproj = ws + OFF_HPROJ;
  float* Q     = ws + OFF_Q;
  float* u     = ws + OFF_U;
  int*   tok   = (int*)(ws + OFF_TOK);
  ushort* bfb  = (ushort*)(ws + OFF_USH);
  ushort* ht_hi = bfb + U_HT_HI;
  ushort* ht_lo = bfb + U_HT_LO;
  ushort* xc_hi = bfb + U_XC_HI;
  ushort* xc_lo = bfb + U_XC_LO;
  ushort* c2_hi = bfb + U_C2_HI;
  ushort* c2_lo = bfb + U_C2_LO;
  ushort* h_hi  = bfb + U_H_HI;
  ushort* h_lo  = bfb + U_H_LO;
  float* PBUF  = ws + OFF_PBUF;
  float* out   = (float*)d_out;

  // prologue scratch (reuses step-loop ushort areas before their first use)
  ushort* hv_hi = xc_hi;  // 64*512 fits in 64*2848
  ushort* hv_lo = xc_lo;
  ushort* t_hi  = c2_hi;  // 64*1824 fits in 64*2848
  ushort* t_lo  = c2_lo;

  auto cdiv = [](int a, int b) { return (a + b - 1) / b; };
  const int zlog = (ws_size >= NEED_Z10) ? 10 : 8;
  const int kclog = (zlog == 10) ? 288 : 360;

  // ---- prologue ----
  hmean_kernel<<<cdiv(B * DENC, 256), 256, 0, stream>>>(h, havg);
  split_pad<<<cdiv(B * DENC, 256), 256, 0, stream>>>(havg, DENC, DENC, B, hv_hi, hv_lo);
  // h0: tmp = relu(havg @ ih_W1.T + b1); ht = tmp @ ih_W2.T + b2
  mfma_gemm3<<<dim3(cdiv(DD, 128), 1, 4), 256, 0, stream>>>(
      hv_hi, hv_lo, DENC, ih_W1, DENC, DENC, ih_W1, DENC, PBUF, B, DD, DENC, 128);
  reduce_k<1><<<cdiv(B * DD / 4, 256), 256, 0, stream>>>(
      PBUF, 4, B * DD / 4, (size_t)B * DD, DD, ih_b1, tmp);
  split_pad<<<cdiv(B * DDP, 256), 256, 0, stream>>>(tmp, DD, DDP, B, t_hi, t_lo);
  mfma_gemm3<<<dim3(cdiv(DD, 128), 1, 15), 256, 0, stream>>>(
      t_hi, t_lo, DDP, ih_W2, DD, DD, ih_W2, DD, PBUF, B, DD, DD, 120);
  reduce_k<0><<<cdiv(B * DD / 4, 256), 256, 0, stream>>>(
      PBUF, 15, B * DD / 4, (size_t)B * DD, DD, ih_b2, ht);
  // c0: same with ic_*
  mfma_gemm3<<<dim3(cdiv(DD, 128), 1, 4), 256, 0, stream>>>(
      hv_hi, hv_lo, DENC, ic_W1, DENC, DENC, ic_W1, DENC, PBUF, B, DD, DENC, 128);
  reduce_k<1><<<cdiv(B * DD / 4, 256), 256, 0, stream>>>(
      PBUF, 4, B * DD / 4, (size_t)B * DD, DD, ic_b1, tmp);
  split_pad<<<cdiv(B * DDP, 256), 256, 0, stream>>>(tmp, DD, DDP, B, t_hi, t_lo);
  mfma_gemm3<<<dim3(cdiv(DD, 128), 1, 15), 256, 0, stream>>>(
      t_hi, t_lo, DDP, ic_W2, DD, DD, ic_W2, DD, PBUF, B, DD, DD, 120);
  reduce_k<0><<<cdiv(B * DD / 4, 256), 256, 0, stream>>>(
      PBUF, 15, B * DD / 4, (size_t)B * DD, DD, ic_b2, ct);
  // splits for step loop
  split_pad<<<cdiv(B * DDP, 256), 256, 0, stream>>>(ht, DD, DDP, B, ht_hi, ht_lo);
  split_pad<<<cdiv(S * B * DENC, 256), 256, 0, stream>>>(h, DENC, DENC, S * B, h_hi, h_lo);
  // Hproj = h @ W1h.T + attn_b1  (z=1, K=512, P=Hproj buffer directly)
  mfma_gemm3<<<dim3(cdiv(DD, 128), S * B / 64, 1), 256, 0, stream>>>(
      h_hi, h_lo, DENC, attn_W1 + DD, DD + DENC, DENC, attn_W1 + DD, DD + DENC,
      Hproj, S * B, DD, DENC, DENC);
  reduce_k<0><<<cdiv(S * B * DD / 4, 256), 256, 0, stream>>>(
      Hproj, 1, S * B * DD / 4, (size_t)S * B * DD, DD, attn_b1, Hproj);
  zero_tok<<<1, 64, 0, stream>>>(tok);

  // ---- decode steps ----
  for (int t = 0; t < T - 1; ++t) {
    // Q = ht @ W1q.T  (z=15, kchunk=120: 15*120=1800=K exactly)
    mfma_gemm3<<<dim3(cdiv(DD, 128), 1, 15), 256, 0, stream>>>(
        ht_hi, ht_lo, DDP, attn_W1, DD + DENC, DD, attn_W1, DD + DENC,
        PBUF, B, DD, DD, 120);
    reduce_k<0><<<cdiv(B * DD / 4, 256), 256, 0, stream>>>(
        PBUF, 15, B * DD / 4, (size_t)B * DD, DD, nullptr, Q);
    attn_u_kernel<<<dim3(S, B), 256, 0, stream>>>(Q, Hproj, attn_w2, attn_b2, u);
    softmax_ctx_pack<<<dim3(B, 4), 256, 0, stream>>>(u, h, ht, beta_w, beta_b, emb,
        E + (size_t)t * B, tok, xc_hi, xc_lo, c2_hi, c2_lo);
    // gates = xcat @ [W_ih | W_hh].T  (z=8, kchunk=384: 3072 >= 2824)
    mfma_gemm3<<<dim3(cdiv(G4, 128), 1, 8), 256, 0, stream>>>(
        xc_hi, xc_lo, KCP, W_ih, DE + DENC, DE + DENC, W_hh, DD,
        PBUF, B, G4, KC, 384);
    lstm_fused<<<cdiv(B * DD, 256), 256, 0, stream>>>(
        PBUF, 8, b_ih, b_hh, ct, ht, c2_hi, c2_lo, ht_hi, ht_lo);
    // logits = cat2 @ out_W.T  (z=zlog) -> d_out[t]
    float* logits_t = out + (size_t)t * B * V;
    mfma_gemm3<<<dim3(cdiv(V, 128), 1, zlog), 256, 0, stream>>>(
        c2_hi, c2_lo, KCP, out_W, KC, KC, out_W, KC,
        PBUF, B, V, KC, kclog);
    reduce_k<0><<<cdiv(B * V / 4, 256), 256, 0, stream>>>(
        PBUF, zlog, B * V / 4, (size_t)B * V, V, out_b, logits_t);
    argmax_kernel<<<B, 256, 0, stream>>>(logits_t, tok);
  }
  (void)in_sizes; (void)n_in; (void)out_size; (void)ws_size;
}